// Round 1
// baseline (95.661 us; speedup 1.0000x reference)
//
#include <hip/hip_runtime.h>
#include <math.h>

#define KORD 10
#define DF 64
#define TPB 256

typedef __attribute__((ext_vector_type(8))) short short8;
typedef __attribute__((ext_vector_type(4))) float floatx4;

// Binomial table C(n,k), n,k <= 10
__constant__ int c_binom[11][11] = {
{1,0,0,0,0,0,0,0,0,0,0},
{1,1,0,0,0,0,0,0,0,0,0},
{1,2,1,0,0,0,0,0,0,0,0},
{1,3,3,1,0,0,0,0,0,0,0},
{1,4,6,4,1,0,0,0,0,0,0},
{1,5,10,10,5,1,0,0,0,0,0},
{1,6,15,20,15,6,1,0,0,0,0},
{1,7,21,35,35,21,7,1,0,0,0},
{1,8,28,56,70,56,28,8,1,0,0},
{1,9,36,84,126,126,84,36,9,1,0},
{1,10,45,120,210,252,210,120,45,10,1}};

// fp32 -> bf16 (RNE) and back
__device__ inline short f2bf(float f) {
    unsigned u = __builtin_bit_cast(unsigned, f);
    unsigned r = (u + 0x7fffu + ((u >> 16) & 1u)) >> 16;
    return (short)r;
}
__device__ inline float bf2f(short s) {
    unsigned u = ((unsigned)(unsigned short)s) << 16;
    return __builtin_bit_cast(float, u);
}

// Grid-wide barrier (general-coe path only; grid co-resident by construction).
// Self-heals the harness's 0xAA ws-poison: count <= gridDim (391) and
// generation <= ~50 never equal 0xAAAAAAAA, so the CAS is inert afterwards.
__device__ inline void gsync(int* bar) {
    __syncthreads();
    if (threadIdx.x == 0) {
        atomicCAS(&bar[0], (int)0xAAAAAAAA, 0);
        atomicCAS(&bar[1], (int)0xAAAAAAAA, 0);
        __threadfence();
        int gen = __hip_atomic_load(&bar[1], __ATOMIC_RELAXED, __HIP_MEMORY_SCOPE_AGENT);
        if (__hip_atomic_fetch_add(&bar[0], 1, __ATOMIC_ACQ_REL,
                                   __HIP_MEMORY_SCOPE_AGENT) == (int)gridDim.x - 1) {
            __hip_atomic_store(&bar[0], 0, __ATOMIC_RELAXED, __HIP_MEMORY_SCOPE_AGENT);
            __hip_atomic_fetch_add(&bar[1], 1, __ATOMIC_RELEASE, __HIP_MEMORY_SCOPE_AGENT);
        } else {
            while (__hip_atomic_load(&bar[1], __ATOMIC_ACQUIRE,
                                     __HIP_MEMORY_SCOPE_AGENT) == gen)
                __builtin_amdgcn_s_sleep(2);
        }
        __threadfence();
    }
    __syncthreads();
}

// deg + anorm (general-coe path only)
__device__ void prep_path(const int* __restrict__ src, const int* __restrict__ dst,
                          float* __restrict__ deg, float* __restrict__ anorm,
                          int* bar, int N, int E) {
    const int tid = blockIdx.x * TPB + threadIdx.x;
    const int nthr = gridDim.x * TPB;
    for (int i = tid; i < N; i += nthr) deg[i] = 0.f;
    gsync(bar);
    for (int e = tid; e < E; e += nthr) atomicAdd(&deg[src[e]], 1.0f);
    gsync(bar);
    for (int e = tid; e < E; e += nthr) {
        float ds = deg[src[e]], dd = deg[dst[e]];
        float is = ds > 0.f ? 1.0f / sqrtf(ds) : 0.f;
        float id = dd > 0.f ? 1.0f / sqrtf(dd) : 0.f;
        anorm[e] = is * id;
    }
}

// acc = sum_m g[m] A^m in  (general-coe path only; ends with a full gsync)
__device__ void prop_path(const float* __restrict__ in, float* __restrict__ acc,
                          float* __restrict__ bufA, float* __restrict__ bufB,
                          const int* __restrict__ src, const int* __restrict__ dst,
                          const float* __restrict__ anorm, const float* sg,
                          int* bar, int N, int E) {
    const int tid = blockIdx.x * TPB + threadIdx.x;
    const int nthr = gridDim.x * TPB;
    const int nd4 = N * DF / 4;
    float g0 = sg[0];
    const float4* in4 = (const float4*)in;
    float4* acc4 = (float4*)acc;
    for (int i = tid; i < nd4; i += nthr) {
        float4 v = in4[i];
        acc4[i] = make_float4(g0 * v.x, g0 * v.y, g0 * v.z, g0 * v.w);
    }
    const float* cur = in;
    for (int m = 1; m <= KORD; ++m) {
        float* nxt = (m & 1) ? bufA : bufB;
        float4* nxt4 = (float4*)nxt;
        for (int i = tid; i < nd4; i += nthr)
            nxt4[i] = make_float4(0.f, 0.f, 0.f, 0.f);
        gsync(bar);
        int tot = E * 16;
        for (int t = tid; t < tot; t += nthr) {
            int e = t >> 4, f = t & 15;
            float a = anorm[e];
            float4 v = ((const float4*)(cur + (size_t)src[e] * DF))[f];
            float* o = nxt + (size_t)dst[e] * DF + f * 4;
            atomicAdd(o + 0, a * v.x);
            atomicAdd(o + 1, a * v.y);
            atomicAdd(o + 2, a * v.z);
            atomicAdd(o + 3, a * v.w);
        }
        gsync(bar);
        float gm = sg[m];
        if (gm != 0.f) {
            const float4* y4 = (const float4*)nxt;
            for (int i = tid; i < nd4; i += nthr) {
                float4 v = y4[i];
                float4 a = acc4[i];
                a.x += gm * v.x; a.y += gm * v.y; a.z += gm * v.z; a.w += gm * v.w;
                acc4[i] = a;
            }
        }
        cur = nxt;
    }
    gsync(bar);   // acc complete, visible to all blocks
}

// Split a scaled fp32 A-tile (8x floatx4, MFMA A-layout) into hi/lo bf16 frags.
__device__ inline void a_split(const floatx4 a_raw[8], float scale,
                               short8 Ah[4], short8 Al[4]) {
#pragma unroll
    for (int f = 0; f < 4; ++f) {
#pragma unroll
        for (int h = 0; h < 2; ++h) {
            floatx4 v = a_raw[f * 2 + h];
#pragma unroll
            for (int e = 0; e < 4; ++e) {
                float x = v[e] * scale;
                short hi = f2bf(x);
                Ah[f][h * 4 + e] = hi;
                Al[f][h * 4 + e] = f2bf(x - bf2f(hi));
            }
        }
    }
}

// 48 MFMAs: 32 rows x 64 cols, K=64, split-precision (AhBh + AhBl + AlBh).
__device__ inline void mfma_all(const short8 Ah[4], const short8 Al[4],
                                const short* sBh, const short* sBl,
                                int i15, int q, floatx4 acc[8]) {
#pragma unroll
    for (int colg = 0; colg < 4; ++colg) {
        int n = colg * 16 + i15;
#pragma unroll
        for (int kh = 0; kh < 2; ++kh) {
            short8 Bh = *(const short8*)&sBh[n * 72 + kh * 32 + q * 8];
            short8 Bl = *(const short8*)&sBl[n * 72 + kh * 32 + q * 8];
#pragma unroll
            for (int rg = 0; rg < 2; ++rg) {
                int f = rg * 2 + kh, c = colg * 2 + rg;
                acc[c] = __builtin_amdgcn_mfma_f32_16x16x32_bf16(Al[f], Bh, acc[c], 0, 0, 0);
                acc[c] = __builtin_amdgcn_mfma_f32_16x16x32_bf16(Ah[f], Bl, acc[c], 0, 0, 0);
                acc[c] = __builtin_amdgcn_mfma_f32_16x16x32_bf16(Ah[f], Bh, acc[c], 0, 0, 0);
            }
        }
    }
}

// Stage W^T (hi/lo bf16) into LDS from 16 per-thread fp32 values.
__device__ inline void stage_WT_regs(const float wr[16], int t,
                                     short* sBh, short* sBl) {
    const int n = t & 63, kq = t >> 6;
    short h8[16], l8[16];
#pragma unroll
    for (int kk = 0; kk < 16; ++kk) {
        short hi = f2bf(wr[kk]);
        h8[kk] = hi;
        l8[kk] = f2bf(wr[kk] - bf2f(hi));
    }
    *(short8*)&sBh[n * 72 + kq * 16]     = *(short8*)&h8[0];
    *(short8*)&sBh[n * 72 + kq * 16 + 8] = *(short8*)&h8[8];
    *(short8*)&sBl[n * 72 + kq * 16]     = *(short8*)&l8[0];
    *(short8*)&sBl[n * 72 + kq * 16 + 8] = *(short8*)&l8[8];
}

// Slow-path MFMA GEMM from a global fp32 input (verified in R4).
template <bool FUSE_FC>
__device__ void gemm_mfma(const float* __restrict__ src_, float scale,
                          const float* __restrict__ W, const float* __restrict__ bias,
                          const float* __restrict__ fcw, const float* __restrict__ fcb,
                          float* __restrict__ hout, int N,
                          short* sBh, short* sBl) {
    const int t = threadIdx.x;
    const int lane = t & 63, wv = t >> 6, q = lane >> 4, i15 = lane & 15;
    const int rBase = blockIdx.x * 128 + wv * 32;

    floatx4 a_raw[8];
#pragma unroll
    for (int rg = 0; rg < 2; ++rg) {
        int row = rBase + rg * 16 + i15;
        const float* rp = src_ + (size_t)row * DF + q * 8;
        bool ok = row < N;
#pragma unroll
        for (int kh = 0; kh < 2; ++kh)
#pragma unroll
            for (int h = 0; h < 2; ++h) {
                int idx = (rg * 2 + kh) * 2 + h;
                a_raw[idx] = ok ? *(const floatx4*)(rp + kh * 32 + h * 4) : (floatx4)(0.f);
            }
    }
    {
        const int n = t & 63, kq = t >> 6;
        float wr[16];
#pragma unroll
        for (int kk = 0; kk < 16; ++kk) wr[kk] = W[(size_t)(kq * 16 + kk) * DF + n];
        stage_WT_regs(wr, t, sBh, sBl);
    }
    short8 Ah[4], Al[4];
    a_split(a_raw, scale, Ah, Al);
    __syncthreads();

    floatx4 acc[8];
#pragma unroll
    for (int j = 0; j < 8; ++j) acc[j] = (floatx4)(0.f);
    mfma_all(Ah, Al, sBh, sBl, i15, q, acc);

    if (FUSE_FC) {
        float fb = fcb[0], bv[4], wv4[4];
#pragma unroll
        for (int c = 0; c < 4; ++c) { bv[c] = bias[c * 16 + i15]; wv4[c] = fcw[c * 16 + i15]; }
#pragma unroll
        for (int rg = 0; rg < 2; ++rg)
#pragma unroll
            for (int i = 0; i < 4; ++i) {
                float p = 0.f;
#pragma unroll
                for (int c = 0; c < 4; ++c) {
                    float v = acc[c * 2 + rg][i] + bv[c];
                    v = v > 0.f ? v : 0.f;
                    p += v * wv4[c];
                }
                p += __shfl_xor(p, 1, 64);
                p += __shfl_xor(p, 2, 64);
                p += __shfl_xor(p, 4, 64);
                p += __shfl_xor(p, 8, 64);
                int row = rBase + rg * 16 + q * 4 + i;
                if (i15 == 0 && row < N) hout[row] = p + fb;
            }
    } else {
        float bv[4];
#pragma unroll
        for (int c = 0; c < 4; ++c) bv[c] = bias[c * 16 + i15];
#pragma unroll
        for (int rg = 0; rg < 2; ++rg)
#pragma unroll
            for (int i = 0; i < 4; ++i) {
                int row = rBase + rg * 16 + q * 4 + i;
                if (row < N)
#pragma unroll
                    for (int c = 0; c < 4; ++c) {
                        float v = acc[c * 2 + rg][i] + bv[c];
                        v = v > 0.f ? v : 0.f;
                        hout[(size_t)row * DF + c * 16 + i15] = v;
                    }
            }
    }
}

// Whole network, one launch. Fast path (g[m>=1]==0): both layers + fc in-block,
// h1 lives only in LDS (layer-2 A rows == layer-1 output rows of SAME block).
__global__ __launch_bounds__(TPB, 2) void fused_net(
        const float* __restrict__ x, const float* __restrict__ W1,
        const float* __restrict__ b1, const float* __restrict__ W2,
        const float* __restrict__ b2, const float* __restrict__ fcw,
        const float* __restrict__ fcb, float* __restrict__ out,
        const int* __restrict__ src, const int* __restrict__ dst,
        const float* __restrict__ coe,
        float* deg, float* anorm, float* bufA, float* bufB, float* acc,
        float* h1, int* bar, int N, int E) {
    __shared__ short sBh[64 * 72];
    __shared__ short sBl[64 * 72];
    __shared__ float ldsT[128 * 68];    // layer-1 output, C/D -> A layout bridge
    __shared__ float sCoe[12];
    __shared__ float sg[12];
    __shared__ int   sfl[1];

    const int t = threadIdx.x;
    if (t <= KORD) sCoe[t] = coe[t];
    __syncthreads();
    if (t <= KORD) {
        const int m = t;
        float s = 0.f;
        for (int j = 0; j <= KORD; ++j) {
            float c = sCoe[j]; c = c > 0.f ? c : 0.f;
            float qq = (float)c_binom[KORD][j] * (1.0f / 1024.0f) * c;
            int w = 0;
            int amax = j < m ? j : m;
            for (int a = 0; a <= amax; ++a) {
                int b = m - a;
                if (b <= KORD - j) {
                    int term = c_binom[j][a] * c_binom[KORD - j][b];
                    w += (a & 1) ? -term : term;
                }
            }
            s += qq * (float)w;
        }
        sg[m] = s;
    }
    __syncthreads();
    if (t == 0) {
        int any = 0;
        for (int m = KORD; m >= 1; --m) if (sg[m] != 0.f) any = 1;
        sfl[0] = any;
    }
    __syncthreads();
    const int fl = sfl[0];          // uniform across ALL blocks (same coe)
    const float g0 = sg[0];

    if (fl) {  // general-coe path: grid-synced, h1 via global
        prep_path(src, dst, deg, anorm, bar, N, E);
        prop_path(x, acc, bufA, bufB, src, dst, anorm, sg, bar, N, E);
        gemm_mfma<false>(acc, 1.f, W1, b1, fcw, fcb, h1, N, sBh, sBl);
        gsync(bar);                 // h1 visible to all blocks
        prop_path(h1, acc, bufA, bufB, src, dst, anorm, sg, bar, N, E);
        gemm_mfma<true>(acc, 1.f, W2, b2, fcw, fcb, out, N, sBh, sBl);
        return;
    }

    // ---- fast path: entire net in one block pass ----
    const int lane = t & 63, wv = t >> 6, q = lane >> 4, i15 = lane & 15;
    const int rBase = blockIdx.x * 128 + wv * 32;

    // A1 loads (x, MFMA A-layout)
    floatx4 a_raw[8];
#pragma unroll
    for (int rg = 0; rg < 2; ++rg) {
        int row = rBase + rg * 16 + i15;
        const float* rp = x + (size_t)row * DF + q * 8;
        bool ok = row < N;
#pragma unroll
        for (int kh = 0; kh < 2; ++kh)
#pragma unroll
            for (int h = 0; h < 2; ++h) {
                int idx = (rg * 2 + kh) * 2 + h;
                a_raw[idx] = ok ? *(const floatx4*)(rp + kh * 32 + h * 4) : (floatx4)(0.f);
            }
    }
    // stage W1 -> LDS; prefetch W2 into registers (hidden behind mfma1)
    float w2r[16];
    {
        const int n = t & 63, kq = t >> 6;
        float wr[16];
#pragma unroll
        for (int kk = 0; kk < 16; ++kk) {
            wr[kk]  = W1[(size_t)(kq * 16 + kk) * DF + n];
            w2r[kk] = W2[(size_t)(kq * 16 + kk) * DF + n];
        }
        stage_WT_regs(wr, t, sBh, sBl);
    }
    short8 Ah[4], Al[4];
    a_split(a_raw, g0, Ah, Al);
    __syncthreads();

    floatx4 acc1[8];
#pragma unroll
    for (int j = 0; j < 8; ++j) acc1[j] = (floatx4)(0.f);
    mfma_all(Ah, Al, sBh, sBl, i15, q, acc1);

    // layer-1 epilogue: relu -> ldsT (C/D layout: row=q*4+i, col=i15 within tile)
    {
        float bv[4];
#pragma unroll
        for (int c = 0; c < 4; ++c) bv[c] = b1[c * 16 + i15];
#pragma unroll
        for (int rg = 0; rg < 2; ++rg)
#pragma unroll
            for (int i = 0; i < 4; ++i) {
                int lr = wv * 32 + rg * 16 + q * 4 + i;
#pragma unroll
                for (int c = 0; c < 4; ++c) {
                    float v = acc1[c * 2 + rg][i] + bv[c];
                    v = v > 0.f ? v : 0.f;
                    ldsT[lr * 68 + c * 16 + i15] = v;
                }
            }
    }
    __syncthreads();   // ldsT complete; sB reads (mfma1) done -> safe to restage

    stage_WT_regs(w2r, t, sBh, sBl);
    // A2 from ldsT (same rows this block just produced), scale g0
    floatx4 a2[8];
#pragma unroll
    for (int rg = 0; rg < 2; ++rg) {
        int lr = wv * 32 + rg * 16 + i15;
#pragma unroll
        for (int kh = 0; kh < 2; ++kh)
#pragma unroll
            for (int h = 0; h < 2; ++h)
                a2[(rg * 2 + kh) * 2 + h] =
                    *(const floatx4*)&ldsT[lr * 68 + kh * 32 + q * 8 + h * 4];
    }
    a_split(a2, g0, Ah, Al);
    __syncthreads();   // sB (W2) ready

    floatx4 acc2[8];
#pragma unroll
    for (int j = 0; j < 8; ++j) acc2[j] = (floatx4)(0.f);
    mfma_all(Ah, Al, sBh, sBl, i15, q, acc2);

    // fc epilogue
    {
        float fb = fcb[0], bv[4], wv4[4];
#pragma unroll
        for (int c = 0; c < 4; ++c) { bv[c] = b2[c * 16 + i15]; wv4[c] = fcw[c * 16 + i15]; }
#pragma unroll
        for (int rg = 0; rg < 2; ++rg)
#pragma unroll
            for (int i = 0; i < 4; ++i) {
                float p = 0.f;
#pragma unroll
                for (int c = 0; c < 4; ++c) {
                    float v = acc2[c * 2 + rg][i] + bv[c];
                    v = v > 0.f ? v : 0.f;
                    p += v * wv4[c];
                }
                p += __shfl_xor(p, 1, 64);
                p += __shfl_xor(p, 2, 64);
                p += __shfl_xor(p, 4, 64);
                p += __shfl_xor(p, 8, 64);
                int row = rBase + rg * 16 + q * 4 + i;
                if (i15 == 0 && row < N) out[row] = p + fb;
            }
    }
}

extern "C" void kernel_launch(void* const* d_in, const int* in_sizes, int n_in,
                              void* d_out, int out_size, void* d_ws, size_t ws_size,
                              hipStream_t stream) {
    const float* x   = (const float*)d_in[0];
    const int*   ei  = (const int*)d_in[1];
    const float* coe = (const float*)d_in[2];
    const float* W1  = (const float*)d_in[3];
    const float* b1  = (const float*)d_in[4];
    const float* W2  = (const float*)d_in[5];
    const float* b2  = (const float*)d_in[6];
    const float* fcw = (const float*)d_in[7];
    const float* fcb = (const float*)d_in[8];
    float* out = (float*)d_out;

    const int ND = in_sizes[0];        // N*64
    const int N  = ND / DF;            // 50000
    const int E  = in_sizes[1] / 2;    // 800000
    const int* src = ei;
    const int* dst = ei + E;

    size_t off = 0;
    auto alloc = [&](size_t bytes) -> char* {
        char* p = (char*)d_ws + off;
        off += (bytes + 255) & ~(size_t)255;
        return p;
    };
    int*   bar   = (int*)alloc(64);
    float* deg   = (float*)alloc((size_t)N * 4);
    float* anorm = (float*)alloc((size_t)E * 4);
    float* bufA  = (float*)alloc((size_t)ND * 4);
    float* bufB  = (float*)alloc((size_t)ND * 4);
    float* acc   = (float*)alloc((size_t)ND * 4);
    float* h1    = (float*)alloc((size_t)ND * 4);
    (void)ws_size;

    const int NB = (N + 127) / 128;    // 391 blocks <= 512 co-residency cap

    fused_net<<<NB, TPB, 0, stream>>>(x, W1, b1, W2, b2, fcw, fcb, out,
                                      src, dst, coe, deg, anorm,
                                      bufA, bufB, acc, h1, bar, N, E);
}

// Round 2
// 94.132 us; speedup vs baseline: 1.0162x; 1.0162x over previous
//
#include <hip/hip_runtime.h>
#include <math.h>

#define KORD 10
#define DF 64
#define TPB 256
#define RPB 64     // rows per block (16 per wave, 4 waves)

typedef __attribute__((ext_vector_type(8))) short short8;
typedef __attribute__((ext_vector_type(4))) float floatx4;

// Binomial table C(n,k), n,k <= 10
__constant__ int c_binom[11][11] = {
{1,0,0,0,0,0,0,0,0,0,0},
{1,1,0,0,0,0,0,0,0,0,0},
{1,2,1,0,0,0,0,0,0,0,0},
{1,3,3,1,0,0,0,0,0,0,0},
{1,4,6,4,1,0,0,0,0,0,0},
{1,5,10,10,5,1,0,0,0,0,0},
{1,6,15,20,15,6,1,0,0,0,0},
{1,7,21,35,35,21,7,1,0,0,0},
{1,8,28,56,70,56,28,8,1,0,0},
{1,9,36,84,126,126,84,36,9,1,0},
{1,10,45,120,210,252,210,120,45,10,1}};

// fp32 -> bf16 (RNE) and back
__device__ inline short f2bf(float f) {
    unsigned u = __builtin_bit_cast(unsigned, f);
    unsigned r = (u + 0x7fffu + ((u >> 16) & 1u)) >> 16;
    return (short)r;
}
__device__ inline float bf2f(short s) {
    unsigned u = ((unsigned)(unsigned short)s) << 16;
    return __builtin_bit_cast(float, u);
}

// Grid-wide barrier (general-coe path only; grid co-resident by construction:
// 782 blocks <= 4 blocks/CU * 256 CU). Self-heals the harness's 0xAA ws-poison.
__device__ inline void gsync(int* bar) {
    __syncthreads();
    if (threadIdx.x == 0) {
        atomicCAS(&bar[0], (int)0xAAAAAAAA, 0);
        atomicCAS(&bar[1], (int)0xAAAAAAAA, 0);
        __threadfence();
        int gen = __hip_atomic_load(&bar[1], __ATOMIC_RELAXED, __HIP_MEMORY_SCOPE_AGENT);
        if (__hip_atomic_fetch_add(&bar[0], 1, __ATOMIC_ACQ_REL,
                                   __HIP_MEMORY_SCOPE_AGENT) == (int)gridDim.x - 1) {
            __hip_atomic_store(&bar[0], 0, __ATOMIC_RELAXED, __HIP_MEMORY_SCOPE_AGENT);
            __hip_atomic_fetch_add(&bar[1], 1, __ATOMIC_RELEASE, __HIP_MEMORY_SCOPE_AGENT);
        } else {
            while (__hip_atomic_load(&bar[1], __ATOMIC_ACQUIRE,
                                     __HIP_MEMORY_SCOPE_AGENT) == gen)
                __builtin_amdgcn_s_sleep(2);
        }
        __threadfence();
    }
    __syncthreads();
}

// deg + anorm (general-coe path only)
__device__ void prep_path(const int* __restrict__ src, const int* __restrict__ dst,
                          float* __restrict__ deg, float* __restrict__ anorm,
                          int* bar, int N, int E) {
    const int tid = blockIdx.x * TPB + threadIdx.x;
    const int nthr = gridDim.x * TPB;
    for (int i = tid; i < N; i += nthr) deg[i] = 0.f;
    gsync(bar);
    for (int e = tid; e < E; e += nthr) atomicAdd(&deg[src[e]], 1.0f);
    gsync(bar);
    for (int e = tid; e < E; e += nthr) {
        float ds = deg[src[e]], dd = deg[dst[e]];
        float is = ds > 0.f ? 1.0f / sqrtf(ds) : 0.f;
        float id = dd > 0.f ? 1.0f / sqrtf(dd) : 0.f;
        anorm[e] = is * id;
    }
}

// acc = sum_m g[m] A^m in  (general-coe path only; ends with a full gsync)
__device__ void prop_path(const float* __restrict__ in, float* __restrict__ acc,
                          float* __restrict__ bufA, float* __restrict__ bufB,
                          const int* __restrict__ src, const int* __restrict__ dst,
                          const float* __restrict__ anorm, const float* sg,
                          int* bar, int N, int E) {
    const int tid = blockIdx.x * TPB + threadIdx.x;
    const int nthr = gridDim.x * TPB;
    const int nd4 = N * DF / 4;
    float g0 = sg[0];
    const float4* in4 = (const float4*)in;
    float4* acc4 = (float4*)acc;
    for (int i = tid; i < nd4; i += nthr) {
        float4 v = in4[i];
        acc4[i] = make_float4(g0 * v.x, g0 * v.y, g0 * v.z, g0 * v.w);
    }
    const float* cur = in;
    for (int m = 1; m <= KORD; ++m) {
        float* nxt = (m & 1) ? bufA : bufB;
        float4* nxt4 = (float4*)nxt;
        for (int i = tid; i < nd4; i += nthr)
            nxt4[i] = make_float4(0.f, 0.f, 0.f, 0.f);
        gsync(bar);
        int tot = E * 16;
        for (int t = tid; t < tot; t += nthr) {
            int e = t >> 4, f = t & 15;
            float a = anorm[e];
            float4 v = ((const float4*)(cur + (size_t)src[e] * DF))[f];
            float* o = nxt + (size_t)dst[e] * DF + f * 4;
            atomicAdd(o + 0, a * v.x);
            atomicAdd(o + 1, a * v.y);
            atomicAdd(o + 2, a * v.z);
            atomicAdd(o + 3, a * v.w);
        }
        gsync(bar);
        float gm = sg[m];
        if (gm != 0.f) {
            const float4* y4 = (const float4*)nxt;
            for (int i = tid; i < nd4; i += nthr) {
                float4 v = y4[i];
                float4 a = acc4[i];
                a.x += gm * v.x; a.y += gm * v.y; a.z += gm * v.z; a.w += gm * v.w;
                acc4[i] = a;
            }
        }
        cur = nxt;
    }
    gsync(bar);   // acc complete, visible to all blocks
}

// Split a scaled fp32 A-tile (4x floatx4 = 16 rows x K=64 slice per lane,
// MFMA A-layout) into hi/lo bf16 frags.
__device__ inline void a_split16(const floatx4 a_raw[4], float scale,
                                 short8 Ah[2], short8 Al[2]) {
#pragma unroll
    for (int f = 0; f < 2; ++f) {
#pragma unroll
        for (int h = 0; h < 2; ++h) {
            floatx4 v = a_raw[f * 2 + h];
#pragma unroll
            for (int e = 0; e < 4; ++e) {
                float x = v[e] * scale;
                short hi = f2bf(x);
                Ah[f][h * 4 + e] = hi;
                Al[f][h * 4 + e] = f2bf(x - bf2f(hi));
            }
        }
    }
}

// 24 MFMAs: 16 rows x 64 cols, K=64, split-precision (AhBh + AhBl + AlBh).
__device__ inline void mfma_all16(const short8 Ah[2], const short8 Al[2],
                                  const short* sBh, const short* sBl,
                                  int i15, int q, floatx4 acc[4]) {
#pragma unroll
    for (int colg = 0; colg < 4; ++colg) {
        int n = colg * 16 + i15;
#pragma unroll
        for (int kh = 0; kh < 2; ++kh) {
            short8 Bh = *(const short8*)&sBh[n * 72 + kh * 32 + q * 8];
            short8 Bl = *(const short8*)&sBl[n * 72 + kh * 32 + q * 8];
            acc[colg] = __builtin_amdgcn_mfma_f32_16x16x32_bf16(Al[kh], Bh, acc[colg], 0, 0, 0);
            acc[colg] = __builtin_amdgcn_mfma_f32_16x16x32_bf16(Ah[kh], Bl, acc[colg], 0, 0, 0);
            acc[colg] = __builtin_amdgcn_mfma_f32_16x16x32_bf16(Ah[kh], Bh, acc[colg], 0, 0, 0);
        }
    }
}

// Stage W^T (hi/lo bf16) into LDS from 16 per-thread fp32 values.
__device__ inline void stage_WT_regs(const float wr[16], int t,
                                     short* sBh, short* sBl) {
    const int n = t & 63, kq = t >> 6;
    short h8[16], l8[16];
#pragma unroll
    for (int kk = 0; kk < 16; ++kk) {
        short hi = f2bf(wr[kk]);
        h8[kk] = hi;
        l8[kk] = f2bf(wr[kk] - bf2f(hi));
    }
    *(short8*)&sBh[n * 72 + kq * 16]     = *(short8*)&h8[0];
    *(short8*)&sBh[n * 72 + kq * 16 + 8] = *(short8*)&h8[8];
    *(short8*)&sBl[n * 72 + kq * 16]     = *(short8*)&l8[0];
    *(short8*)&sBl[n * 72 + kq * 16 + 8] = *(short8*)&l8[8];
}

// Slow-path MFMA GEMM from a global fp32 input (16 rows per wave).
template <bool FUSE_FC>
__device__ void gemm_mfma(const float* __restrict__ src_, float scale,
                          const float* __restrict__ W, const float* __restrict__ bias,
                          const float* __restrict__ fcw, const float* __restrict__ fcb,
                          float* __restrict__ hout, int N,
                          short* sBh, short* sBl) {
    const int t = threadIdx.x;
    const int lane = t & 63, wv = t >> 6, q = lane >> 4, i15 = lane & 15;
    const int rBase = blockIdx.x * RPB + wv * 16;

    floatx4 a_raw[4];
    {
        int row = rBase + i15;
        const float* rp = src_ + (size_t)row * DF + q * 8;
        bool ok = row < N;
#pragma unroll
        for (int kh = 0; kh < 2; ++kh)
#pragma unroll
            for (int h = 0; h < 2; ++h)
                a_raw[kh * 2 + h] = ok ? *(const floatx4*)(rp + kh * 32 + h * 4)
                                       : (floatx4)(0.f);
    }
    {
        const int n = t & 63, kq = t >> 6;
        float wr[16];
#pragma unroll
        for (int kk = 0; kk < 16; ++kk) wr[kk] = W[(size_t)(kq * 16 + kk) * DF + n];
        stage_WT_regs(wr, t, sBh, sBl);
    }
    short8 Ah[2], Al[2];
    a_split16(a_raw, scale, Ah, Al);
    __syncthreads();

    floatx4 acc[4];
#pragma unroll
    for (int j = 0; j < 4; ++j) acc[j] = (floatx4)(0.f);
    mfma_all16(Ah, Al, sBh, sBl, i15, q, acc);

    if (FUSE_FC) {
        float fb = fcb[0], bv[4], wv4[4];
#pragma unroll
        for (int c = 0; c < 4; ++c) { bv[c] = bias[c * 16 + i15]; wv4[c] = fcw[c * 16 + i15]; }
#pragma unroll
        for (int i = 0; i < 4; ++i) {
            float p = 0.f;
#pragma unroll
            for (int c = 0; c < 4; ++c) {
                float v = acc[c][i] + bv[c];
                v = v > 0.f ? v : 0.f;
                p += v * wv4[c];
            }
            p += __shfl_xor(p, 1, 64);
            p += __shfl_xor(p, 2, 64);
            p += __shfl_xor(p, 4, 64);
            p += __shfl_xor(p, 8, 64);
            int row = rBase + q * 4 + i;
            if (i15 == 0 && row < N) hout[row] = p + fb;
        }
    } else {
        float bv[4];
#pragma unroll
        for (int c = 0; c < 4; ++c) bv[c] = bias[c * 16 + i15];
#pragma unroll
        for (int i = 0; i < 4; ++i) {
            int row = rBase + q * 4 + i;
            if (row < N)
#pragma unroll
                for (int c = 0; c < 4; ++c) {
                    float v = acc[c][i] + bv[c];
                    v = v > 0.f ? v : 0.f;
                    hout[(size_t)row * DF + c * 16 + i15] = v;
                }
        }
    }
}

// Whole network, one launch. Fast path (g[m>=1]==0): both layers + fc in-block,
// h1 lives only in LDS (layer-2 A rows == layer-1 output rows of SAME block).
// Geometry: 16 rows/wave, 64 rows/block, 782 blocks -> ~3 waves/SIMD.
__global__ __launch_bounds__(TPB, 4) void fused_net(
        const float* __restrict__ x, const float* __restrict__ W1,
        const float* __restrict__ b1, const float* __restrict__ W2,
        const float* __restrict__ b2, const float* __restrict__ fcw,
        const float* __restrict__ fcb, float* __restrict__ out,
        const int* __restrict__ src, const int* __restrict__ dst,
        const float* __restrict__ coe,
        float* deg, float* anorm, float* bufA, float* bufB, float* acc,
        float* h1, int* bar, int N, int E) {
    __shared__ short sBh[64 * 72];
    __shared__ short sBl[64 * 72];
    __shared__ float ldsT[RPB * 68];    // layer-1 output, C/D -> A layout bridge
    __shared__ float sCoe[12];
    __shared__ float sg[12];
    __shared__ int   sfl[1];

    const int t = threadIdx.x;
    if (t <= KORD) sCoe[t] = coe[t];
    __syncthreads();
    if (t <= KORD) {
        const int m = t;
        float s = 0.f;
        for (int j = 0; j <= KORD; ++j) {
            float c = sCoe[j]; c = c > 0.f ? c : 0.f;
            float qq = (float)c_binom[KORD][j] * (1.0f / 1024.0f) * c;
            int w = 0;
            int amax = j < m ? j : m;
            for (int a = 0; a <= amax; ++a) {
                int b = m - a;
                if (b <= KORD - j) {
                    int term = c_binom[j][a] * c_binom[KORD - j][b];
                    w += (a & 1) ? -term : term;
                }
            }
            s += qq * (float)w;
        }
        sg[m] = s;
    }
    __syncthreads();
    if (t == 0) {
        int any = 0;
        for (int m = KORD; m >= 1; --m) if (sg[m] != 0.f) any = 1;
        sfl[0] = any;
    }
    __syncthreads();
    const int fl = sfl[0];          // uniform across ALL blocks (same coe)
    const float g0 = sg[0];

    if (fl) {  // general-coe path: grid-synced, h1 via global
        prep_path(src, dst, deg, anorm, bar, N, E);
        prop_path(x, acc, bufA, bufB, src, dst, anorm, sg, bar, N, E);
        gemm_mfma<false>(acc, 1.f, W1, b1, fcw, fcb, h1, N, sBh, sBl);
        gsync(bar);                 // h1 visible to all blocks
        prop_path(h1, acc, bufA, bufB, src, dst, anorm, sg, bar, N, E);
        gemm_mfma<true>(acc, 1.f, W2, b2, fcw, fcb, out, N, sBh, sBl);
        return;
    }

    // ---- fast path: entire net in one block pass ----
    const int lane = t & 63, wv = t >> 6, q = lane >> 4, i15 = lane & 15;
    const int rBase = blockIdx.x * RPB + wv * 16;

    // A1 loads (x, MFMA A-layout): 16 rows per wave, lane row = rBase + i15
    floatx4 a_raw[4];
    {
        int row = rBase + i15;
        const float* rp = x + (size_t)row * DF + q * 8;
        bool ok = row < N;
#pragma unroll
        for (int kh = 0; kh < 2; ++kh)
#pragma unroll
            for (int h = 0; h < 2; ++h)
                a_raw[kh * 2 + h] = ok ? *(const floatx4*)(rp + kh * 32 + h * 4)
                                       : (floatx4)(0.f);
    }
    // stage W1 -> LDS; prefetch W2 into registers (hidden behind mfma1)
    float w2r[16];
    {
        const int n = t & 63, kq = t >> 6;
        float wr[16];
#pragma unroll
        for (int kk = 0; kk < 16; ++kk) {
            wr[kk]  = W1[(size_t)(kq * 16 + kk) * DF + n];
            w2r[kk] = W2[(size_t)(kq * 16 + kk) * DF + n];
        }
        stage_WT_regs(wr, t, sBh, sBl);
    }
    short8 Ah[2], Al[2];
    a_split16(a_raw, g0, Ah, Al);
    __syncthreads();

    floatx4 acc1[4];
#pragma unroll
    for (int j = 0; j < 4; ++j) acc1[j] = (floatx4)(0.f);
    mfma_all16(Ah, Al, sBh, sBl, i15, q, acc1);

    // layer-1 epilogue: relu -> ldsT (C/D layout: row=q*4+i, col=c*16+i15)
    {
        float bv[4];
#pragma unroll
        for (int c = 0; c < 4; ++c) bv[c] = b1[c * 16 + i15];
#pragma unroll
        for (int i = 0; i < 4; ++i) {
            int lr = wv * 16 + q * 4 + i;
#pragma unroll
            for (int c = 0; c < 4; ++c) {
                float v = acc1[c][i] + bv[c];
                v = v > 0.f ? v : 0.f;
                ldsT[lr * 68 + c * 16 + i15] = v;
            }
        }
    }
    __syncthreads();   // ldsT complete; sB reads (mfma1) done -> safe to restage

    stage_WT_regs(w2r, t, sBh, sBl);
    // A2 from ldsT (same rows this block just produced), scale g0
    floatx4 a2[4];
    {
        int lr = wv * 16 + i15;
#pragma unroll
        for (int kh = 0; kh < 2; ++kh)
#pragma unroll
            for (int h = 0; h < 2; ++h)
                a2[kh * 2 + h] =
                    *(const floatx4*)&ldsT[lr * 68 + kh * 32 + q * 8 + h * 4];
    }
    a_split16(a2, g0, Ah, Al);
    __syncthreads();   // sB (W2) ready

    floatx4 acc2[4];
#pragma unroll
    for (int j = 0; j < 4; ++j) acc2[j] = (floatx4)(0.f);
    mfma_all16(Ah, Al, sBh, sBl, i15, q, acc2);

    // fc epilogue
    {
        float fb = fcb[0], bv[4], wv4[4];
#pragma unroll
        for (int c = 0; c < 4; ++c) { bv[c] = b2[c * 16 + i15]; wv4[c] = fcw[c * 16 + i15]; }
#pragma unroll
        for (int i = 0; i < 4; ++i) {
            float p = 0.f;
#pragma unroll
            for (int c = 0; c < 4; ++c) {
                float v = acc2[c][i] + bv[c];
                v = v > 0.f ? v : 0.f;
                p += v * wv4[c];
            }
            p += __shfl_xor(p, 1, 64);
            p += __shfl_xor(p, 2, 64);
            p += __shfl_xor(p, 4, 64);
            p += __shfl_xor(p, 8, 64);
            int row = rBase + q * 4 + i;
            if (i15 == 0 && row < N) out[row] = p + fb;
        }
    }
}

extern "C" void kernel_launch(void* const* d_in, const int* in_sizes, int n_in,
                              void* d_out, int out_size, void* d_ws, size_t ws_size,
                              hipStream_t stream) {
    const float* x   = (const float*)d_in[0];
    const int*   ei  = (const int*)d_in[1];
    const float* coe = (const float*)d_in[2];
    const float* W1  = (const float*)d_in[3];
    const float* b1  = (const float*)d_in[4];
    const float* W2  = (const float*)d_in[5];
    const float* b2  = (const float*)d_in[6];
    const float* fcw = (const float*)d_in[7];
    const float* fcb = (const float*)d_in[8];
    float* out = (float*)d_out;

    const int ND = in_sizes[0];        // N*64
    const int N  = ND / DF;            // 50000
    const int E  = in_sizes[1] / 2;    // 800000
    const int* src = ei;
    const int* dst = ei + E;

    size_t off = 0;
    auto alloc = [&](size_t bytes) -> char* {
        char* p = (char*)d_ws + off;
        off += (bytes + 255) & ~(size_t)255;
        return p;
    };
    int*   bar   = (int*)alloc(64);
    float* deg   = (float*)alloc((size_t)N * 4);
    float* anorm = (float*)alloc((size_t)E * 4);
    float* bufA  = (float*)alloc((size_t)ND * 4);
    float* bufB  = (float*)alloc((size_t)ND * 4);
    float* acc   = (float*)alloc((size_t)ND * 4);
    float* h1    = (float*)alloc((size_t)ND * 4);
    (void)ws_size;

    const int NB = (N + RPB - 1) / RPB;   // 782 blocks <= 4/CU * 256 = 1024 cap

    fused_net<<<NB, TPB, 0, stream>>>(x, W1, b1, W2, b2, fcw, fcb, out,
                                      src, dst, coe, deg, anorm,
                                      bufA, bufB, acc, h1, bar, N, E);
}